// Round 9
// baseline (78.495 us; speedup 1.0000x reference)
//
#include <hip/hip_runtime.h>

#define I_DIM 128
#define H_DIM 64
#define BATCH 8
#define SEQ   4096
#define NBIN  (SEQ/2 + 1)     // 2049 bins of the 4096-rfft (K_hat)
#define NBIN2 (SEQ + 1)       // 4097 bins of the 8192-rfft (Kf)

// LDS swizzle (involution within 16-element chunks) — proven r3-r8.
#define SZ(a) ((a) ^ (((a) >> 4) & 15))

// Module-scope device scratch (graph-capture safe, fully rewritten per call).
__device__ float2 g_Kf[I_DIM * NBIN2];                 // ~4.2 MB
__device__ float2 g_Xf[(size_t)BATCH * I_DIM * SEQ];   // forward spectra, 33.5 MB

__device__ inline float2 cmul(float2 a, float2 b) {
    return make_float2(a.x * b.x - a.y * b.y, a.x * b.y + a.y * b.x);
}
__device__ inline float2 cadd(float2 a, float2 b) { return make_float2(a.x + b.x, a.y + b.y); }
__device__ inline float2 csub(float2 a, float2 b) { return make_float2(a.x - b.x, a.y - b.y); }

// DFT8 (DIF network) — proven r4-r8.
__device__ inline void dft8(float2 a[8]) {
    const float C = 0.70710678118654752f;
    float2 s0 = cadd(a[0], a[4]), s1 = cadd(a[1], a[5]);
    float2 s2 = cadd(a[2], a[6]), s3 = cadd(a[3], a[7]);
    float2 d0 = csub(a[0], a[4]), d1 = csub(a[1], a[5]);
    float2 d2 = csub(a[2], a[6]), d3 = csub(a[3], a[7]);
    d1 = make_float2(C * (d1.x + d1.y), C * (d1.y - d1.x));   // * W8^1
    d2 = make_float2(d2.y, -d2.x);                            // * W8^2 = -i
    d3 = make_float2(C * (d3.y - d3.x), -C * (d3.x + d3.y));  // * W8^3
    {
        float2 p0 = cadd(s0, s2), p1 = cadd(s1, s3);
        float2 m0 = csub(s0, s2), m1 = csub(s1, s3);
        m1 = make_float2(m1.y, -m1.x);
        a[0] = cadd(p0, p1); a[4] = csub(p0, p1);
        a[2] = cadd(m0, m1); a[6] = csub(m0, m1);
    }
    {
        float2 p0 = cadd(d0, d2), p1 = cadd(d1, d3);
        float2 m0 = csub(d0, d2), m1 = csub(d1, d3);
        m1 = make_float2(m1.y, -m1.x);
        a[1] = cadd(p0, p1); a[5] = csub(p0, p1);
        a[3] = cadd(m0, m1); a[7] = csub(m0, m1);
    }
}

__device__ inline void dft4(float2 a[4]) {
    float2 p0 = cadd(a[0], a[2]), p1 = cadd(a[1], a[3]);
    float2 m0 = csub(a[0], a[2]), m1 = csub(a[1], a[3]);
    m1 = make_float2(m1.y, -m1.x);
    a[0] = cadd(p0, p1); a[2] = csub(p0, p1);
    a[1] = cadd(m0, m1); a[3] = csub(m0, m1);
}

// Radix-8 Stockham DIF stage (single-buffer LDS) — proven r3-r8, verbatim.
template <int N, int S, int NT>
__device__ inline void stage8(float2* __restrict__ lds, int tid) {
    constexpr int NB = N / 8;
    constexpr int ITER = (NB + NT - 1) / NT;
    const bool act = (NB >= NT) || (tid < NB);
    float2 d[ITER][8];
#pragma unroll
    for (int b = 0; b < ITER; ++b) {
        const int u = tid + b * NT;
        if (act) {
#pragma unroll
            for (int j = 0; j < 8; ++j)
                d[b][j] = lds[SZ(u + NB * j)];
        }
    }
    __syncthreads();
#pragma unroll
    for (int b = 0; b < ITER; ++b) {
        const int u = tid + b * NT;
        if (act) {
            const int q = u & (S - 1);
            dft8(d[b]);
            if constexpr (S < NB) {
                const float cang = (float)(-6.283185307179586) / (float)N;
                float sn, cs;
                __sincosf(cang * (float)(u - q), &sn, &cs);
                const float2 w = make_float2(cs, sn);
                float2 t = w;
#pragma unroll
                for (int k = 1; k < 8; ++k) {
                    d[b][k] = cmul(d[b][k], t);
                    if (k < 7) t = cmul(t, w);
                }
            }
            const int base = 8 * u - 7 * q;
#pragma unroll
            for (int k = 0; k < 8; ++k)
                lds[SZ(base + k * S)] = d[b][k];
        }
    }
    __syncthreads();
}

// First stage of cfft4096 when input top half is zero (proven r8), inputs
// a0..a3 = z[tid + 512j] supplied by caller (from global x OR from LDS).
// Internal barrier protects the caller's LDS reads before our writes.
__device__ inline void halfzero4096_writeback(float2* __restrict__ lds, int tid,
                                              float2 a0, float2 a1,
                                              float2 a2, float2 a3) {
    const float C = 0.70710678118654752f;
    __syncthreads();
    float2 p0 = cadd(a0, a2), p1 = cadd(a1, a3);
    float2 m0 = csub(a0, a2), m1t = csub(a1, a3);
    float2 m1 = make_float2(m1t.y, -m1t.x);
    float2 b0 = cadd(p0, p1), b4 = csub(p0, p1);
    float2 b2 = cadd(m0, m1), b6 = csub(m0, m1);
    float2 c1 = make_float2(C * (a1.x + a1.y), C * (a1.y - a1.x));
    float2 c2 = make_float2(a2.y, -a2.x);
    float2 c3 = make_float2(C * (a3.y - a3.x), -C * (a3.x + a3.y));
    float2 q0 = cadd(a0, c2), q1 = cadd(c1, c3);
    float2 n0 = csub(a0, c2), n1t = csub(c1, c3);
    float2 n1 = make_float2(n1t.y, -n1t.x);
    float2 b1 = cadd(q0, q1), b5 = csub(q0, q1);
    float2 b3 = cadd(n0, n1), b7 = csub(n0, n1);
    float sn, cs;
    __sincosf((float)(-6.283185307179586 / 4096.0) * (float)tid, &sn, &cs);
    float2 w1 = make_float2(cs, sn);
    float2 w2 = cmul(w1, w1), w3 = cmul(w2, w1), w4 = cmul(w2, w2);
    float2 w5 = cmul(w3, w2), w6 = cmul(w3, w3), w7 = cmul(w4, w3);
    const int base = 8 * tid;
    lds[SZ(base + 0)] = b0;
    lds[SZ(base + 1)] = cmul(b1, w1);
    lds[SZ(base + 2)] = cmul(b2, w2);
    lds[SZ(base + 3)] = cmul(b3, w3);
    lds[SZ(base + 4)] = cmul(b4, w4);
    lds[SZ(base + 5)] = cmul(b5, w5);
    lds[SZ(base + 6)] = cmul(b6, w6);
    lds[SZ(base + 7)] = cmul(b7, w7);
    __syncthreads();
}

// ===========================================================================
// Kernel 1: blocks [0,128)   -> fused khat + kprep for channel i
//           blocks [128,1152) -> forward cfft4096 of packed x row -> g_Xf
// Fusions: x-pack into first stage (global read); last fwd stage writes g_Xf
// from registers (S=512 outputs are per-thread-owned, twiddle-free).
// ===========================================================================
__global__ __launch_bounds__(512) void s4_stage1_kernel(const float* __restrict__ x,
                                                        const float* __restrict__ Bm,
                                                        const float* __restrict__ Cm,
                                                        const float* __restrict__ Lm,
                                                        const float* __restrict__ Pm,
                                                        const float* __restrict__ Qm) {
    __shared__ float2 lds[4096];
    const int tid = threadIdx.x;

    if (blockIdx.x < I_DIM) {
        // ------------------- K-chain path -------------------
        const int i = blockIdx.x;
        // phase 0: K_hat row i -> lds[k] plain (proven r8)
        {
            const float* Brow = Bm + i * H_DIM;
            const float* Crow = Cm + i * H_DIM;
            const float* Lrow = Lm + i * H_DIM;
            const float* Prow = Pm + i * H_DIM;
            const float* Qrow = Qm + i * H_DIM;
            for (int k = tid; k < NBIN; k += 512) {
                float theta = (float)(6.283185307179586 / (double)SEQ) * (float)k;
                float sn, cs;
                sincosf(theta, &sn, &cs);
                float tr = 1.0f - cs, ti = -sn;
                float br = 1.0f + cs, bi = sn;
                float idn = 1.0f / (br * br + bi * bi);
                float gr = 20.0f * (tr * br + ti * bi) * idn;
                float gi = 20.0f * (ti * br - tr * bi) * idn;
                float cr = 2.0f * br * idn;
                float ci = -2.0f * bi * idn;

                float k00r = 0.f, k00i = 0.f, k01r = 0.f, k01i = 0.f;
                float k10r = 0.f, k10i = 0.f, k11r = 0.f, k11i = 0.f;
#pragma unroll 8
                for (int h = 0; h < H_DIM; ++h) {
                    float lam = Lrow[h];
                    float drr = gr - lam;
                    float dii = gi;
                    float im = 1.0f / (drr * drr + dii * dii);
                    float ivr = drr * im;
                    float ivi = -dii * im;
                    float bv = Brow[h], cv = Crow[h], pv = Prow[h], qv = Qrow[h];
                    float cb = cv * bv;
                    float cp = cv * pv;
                    float qb = qv * bv;
                    float qp = qv * pv;
                    k00r += cb * ivr; k00i += cb * ivi;
                    k01r += cp * ivr; k01i += cp * ivi;
                    k10r += qb * ivr; k10i += qb * ivi;
                    k11r += qp * ivr; k11i += qp * ivi;
                }
                float t1r = 1.0f + k11r, t1i = k11i;
                float t2r = k01r * t1r - k01i * t1i;
                float t2i = k01r * t1i + k01i * t1r;
                float t3r = t2r * k10r - t2i * k10i;
                float t3i = t2r * k10i + t2i * k10r;
                float nr = k00r - t3r, ni = k00i - t3i;
                lds[k] = make_float2(cr * nr - ci * ni, cr * ni + ci * nr);
            }
        }
        __syncthreads();

        // fused icfft2048 first stage (radix-4, S=1) + H->z pack (in-reg)
        {
            float2 z[4];
#pragma unroll
            for (int j = 0; j < 4; ++j) {
                int m = tid + (j << 9);
                float2 Hm = lds[m];
                float2 Hc = lds[2048 - m];
                float pr = Hm.x + Hc.x, pi2 = Hm.y - Hc.y;
                float dr = Hm.x - Hc.x, di = Hm.y + Hc.y;
                float sn, cs;
                __sincosf((float)(3.141592653589793 / 2048.0) * (float)m, &sn, &cs);
                float Or = 0.5f * (cs * dr - sn * di);
                float Oi = 0.5f * (sn * dr + cs * di);
                z[j] = make_float2(0.5f * pr - Oi, -(0.5f * pi2 + Or));
            }
            __syncthreads();
            dft4(z);
            float sn, cs;
            __sincosf((float)(-6.283185307179586 / 2048.0) * (float)tid, &sn, &cs);
            float2 w1 = make_float2(cs, sn);
            float2 w2 = cmul(w1, w1);
            float2 w3 = cmul(w2, w1);
            z[1] = cmul(z[1], w1);
            z[2] = cmul(z[2], w2);
            z[3] = cmul(z[3], w3);
            const int base = 4 * tid;
#pragma unroll
            for (int k = 0; k < 4; ++k) lds[SZ(base + k)] = z[k];
            __syncthreads();
        }

        stage8<2048, 4,   512>(lds, tid);
        stage8<2048, 32,  512>(lds, tid);
        stage8<2048, 256, 512>(lds, tid);

        // fused v-pack (conj/2048) + cfft4096 halfzero first stage
        {
            const float s1 = 1.0f / 2048.0f;
            float2 a[4];
#pragma unroll
            for (int j = 0; j < 4; ++j) {
                float2 o = lds[SZ(tid + (j << 9))];
                a[j] = make_float2(o.x * s1, -o.y * s1);
            }
            halfzero4096_writeback(lds, tid, a[0], a[1], a[2], a[3]);
        }

        stage8<4096, 8,   512>(lds, tid);
        stage8<4096, 64,  512>(lds, tid);
        stage8<4096, 512, 512>(lds, tid);

        // untwist -> Kf (proven r8)
        float2* Kfrow = g_Kf + (size_t)i * NBIN2;
#pragma unroll
        for (int r = 0; r < 9; ++r) {
            int m = tid + (r << 9);
            if (m <= 4096) {
                float2 Zq = lds[SZ(m & 4095)];
                float2 Zr = lds[SZ((4096 - m) & 4095)];
                float sn, cs;
                __sincosf((float)(-3.141592653589793 / 4096.0) * (float)m, &sn, &cs);
                float pr = Zq.x + Zr.x, pi2 = Zq.y - Zr.y;
                float dr = Zq.x - Zr.x, di = Zq.y + Zr.y;
                float jt_r = -sn * dr - cs * di;
                float jt_i =  cs * dr - sn * di;
                Kfrow[m] = make_float2(0.5f * (pr - jt_r), 0.5f * (pi2 - jt_i));
            }
        }
    } else {
        // ------------------- forward-FFT path -------------------
        const int blk = blockIdx.x - I_DIM;      // 0..1023
        const int b = blk & 7;                   // batch -> XCD affinity
        const int i = blk >> 3;

        // fused pack: first stage reads x straight from global
        const float* xb = x + (size_t)b * SEQ * I_DIM + i;
        float2 a[4];
#pragma unroll
        for (int j = 0; j < 4; ++j) {
            int n = tid + (j << 9);              // n < 2048
            a[j] = make_float2(xb[(size_t)(2 * n) * I_DIM],
                               xb[(size_t)(2 * n + 1) * I_DIM]);
        }
        halfzero4096_writeback(lds, tid, a[0], a[1], a[2], a[3]);

        stage8<4096, 8,  512>(lds, tid);
        stage8<4096, 64, 512>(lds, tid);

        // last stage (S=512 == N/8: twiddle-free, outputs m = tid+512k are
        // per-thread-owned) fused with the g_Xf store.
        float2 e[8];
#pragma unroll
        for (int j = 0; j < 8; ++j) e[j] = lds[SZ(tid + (j << 9))];
        dft8(e);
        float2* dst = g_Xf + (size_t)blk * SEQ;
#pragma unroll
        for (int k = 0; k < 8; ++k)
            dst[tid + (k << 9)] = e[k];          // coalesced 8B stores
    }
}

// ===========================================================================
// Kernel 2: fused combine + inverse cfft4096 + unpack.
//   inverse stage 1 (S=1) inputs conjZy[tid+512j] computed IN REGISTERS from
//   global Xf pairs {m, 4096-m} and Kf (duplicate-computed per pair; verified
//   identical to the r5 partner-write value by algebraic symmetry).
//   last stage (S=512, twiddle-free) writes y straight from registers.
// ===========================================================================
__global__ __launch_bounds__(512) void s4_stage2_kernel(float* __restrict__ y) {
    __shared__ float2 lds[4096];
    const int tid = threadIdx.x;
    const int blk = blockIdx.x;
    const int b = blk & 7;
    const int i = blk >> 3;
    const float2* Xf = g_Xf + (size_t)blk * SEQ;
    const float2* Kfrow = g_Kf + (size_t)i * NBIN2;

    float2 d[8];
#pragma unroll
    for (int j = 0; j < 8; ++j) {
        int m = tid + (j << 9);
        int mm = (4096 - m) & 4095;
        float2 Zq = Xf[m];
        float2 Zr = Xf[mm];
        float2 Km  = Kfrow[m];
        float2 Km2 = Kfrow[4096 - m];
        float sn, cs;
        __sincosf((float)(-3.141592653589793 / 4096.0) * (float)m, &sn, &cs);
        float pr = Zq.x + Zr.x, pi2 = Zq.y - Zr.y;
        float dr = Zq.x - Zr.x, di = Zq.y + Zr.y;
        float jt_r = -sn * dr - cs * di;
        float jt_i =  cs * dr - sn * di;
        float2 Xm  = make_float2(0.5f * (pr - jt_r),  0.5f * ( pi2 - jt_i));
        float2 Xm2 = make_float2(0.5f * (pr + jt_r),  0.5f * (-pi2 - jt_i));
        float2 Ym  = cmul(Xm,  Km);
        float2 Ym2 = cmul(Xm2, Km2);
        float qr = Ym.x + Ym2.x, qi = Ym.y - Ym2.y;
        float er = Ym.x - Ym2.x, ei = Ym.y + Ym2.y;
        float gr2 = sn * er - cs * ei;
        float gi2 = sn * ei + cs * er;
        d[j] = make_float2(0.5f * (qr + gr2), -0.5f * (qi + gi2));  // conjZy[m]
    }

    // inverse stage 1 (S=1): dft8 + W4096^(tid*k), write SZ(8*tid+k)
    dft8(d);
    {
        float sn, cs;
        __sincosf((float)(-6.283185307179586 / 4096.0) * (float)tid, &sn, &cs);
        float2 w1 = make_float2(cs, sn);
        float2 w2 = cmul(w1, w1), w3 = cmul(w2, w1), w4 = cmul(w2, w2);
        float2 w5 = cmul(w3, w2), w6 = cmul(w3, w3), w7 = cmul(w4, w3);
        d[1] = cmul(d[1], w1); d[2] = cmul(d[2], w2); d[3] = cmul(d[3], w3);
        d[4] = cmul(d[4], w4); d[5] = cmul(d[5], w5); d[6] = cmul(d[6], w6);
        d[7] = cmul(d[7], w7);
    }
    const int base = 8 * tid;
#pragma unroll
    for (int k = 0; k < 8; ++k) lds[SZ(base + k)] = d[k];
    __syncthreads();

    stage8<4096, 8,  512>(lds, tid);
    stage8<4096, 64, 512>(lds, tid);

    // last stage (S=512, twiddle-free) fused with unpack + y store (n<2048)
    float2 e[8];
#pragma unroll
    for (int j = 0; j < 8; ++j) e[j] = lds[SZ(tid + (j << 9))];
    dft8(e);
    const float inv = 1.0f / 4096.0f;
    float* yb = y + (size_t)b * SEQ * I_DIM + i;
#pragma unroll
    for (int k = 0; k < 4; ++k) {
        int n = tid + (k << 9);                  // n < 2048
        yb[(size_t)(2 * n) * I_DIM]     = e[k].x * inv;
        yb[(size_t)(2 * n + 1) * I_DIM] = -e[k].y * inv;
    }
}

// ---------------------------------------------------------------------------
extern "C" void kernel_launch(void* const* d_in, const int* in_sizes, int n_in,
                              void* d_out, int out_size, void* d_ws, size_t ws_size,
                              hipStream_t stream) {
    const float* x  = (const float*)d_in[0];
    const float* Bm = (const float*)d_in[1];
    const float* Cm = (const float*)d_in[2];
    const float* Lm = (const float*)d_in[3];
    const float* Pm = (const float*)d_in[4];
    const float* Qm = (const float*)d_in[5];
    float* out = (float*)d_out;

    s4_stage1_kernel<<<I_DIM + BATCH * I_DIM, 512, 0, stream>>>(x, Bm, Cm, Lm, Pm, Qm);
    s4_stage2_kernel<<<BATCH * I_DIM, 512, 0, stream>>>(out);
}

// Round 10
// 72.167 us; speedup vs baseline: 1.0877x; 1.0877x over previous
//
#include <hip/hip_runtime.h>

#define I_DIM 128
#define H_DIM 64
#define BATCH 8
#define SEQ   4096
#define NBIN  (SEQ/2 + 1)     // 2049
#define NBIN2 (SEQ + 1)       // 4097

// LDS swizzle (involution) — proven r3-r9.
#define SZ(a) ((a) ^ (((a) >> 4) & 15))

// Module-scope device scratch (graph-capture safe, fully rewritten per call).
__device__ float  g_xT[(size_t)BATCH * I_DIM * SEQ];   // x transposed, 16.8 MB
__device__ float2 g_Hh[I_DIM * NBIN];                  // K_hat, 2.1 MB
__device__ float2 g_Kf[I_DIM * NBIN2];                 // 4.2 MB
__device__ float2 g_Xf[(size_t)BATCH * I_DIM * SEQ];   // fwd spectra, 33.5 MB
__device__ float  g_Yt[(size_t)BATCH * I_DIM * SEQ];   // y transposed, 16.8 MB

__device__ inline float2 cmul(float2 a, float2 b) {
    return make_float2(a.x * b.x - a.y * b.y, a.x * b.y + a.y * b.x);
}
__device__ inline float2 cadd(float2 a, float2 b) { return make_float2(a.x + b.x, a.y + b.y); }
__device__ inline float2 csub(float2 a, float2 b) { return make_float2(a.x - b.x, a.y - b.y); }

// DFT8 / DFT4 — proven r4-r9.
__device__ inline void dft8(float2 a[8]) {
    const float C = 0.70710678118654752f;
    float2 s0 = cadd(a[0], a[4]), s1 = cadd(a[1], a[5]);
    float2 s2 = cadd(a[2], a[6]), s3 = cadd(a[3], a[7]);
    float2 d0 = csub(a[0], a[4]), d1 = csub(a[1], a[5]);
    float2 d2 = csub(a[2], a[6]), d3 = csub(a[3], a[7]);
    d1 = make_float2(C * (d1.x + d1.y), C * (d1.y - d1.x));
    d2 = make_float2(d2.y, -d2.x);
    d3 = make_float2(C * (d3.y - d3.x), -C * (d3.x + d3.y));
    {
        float2 p0 = cadd(s0, s2), p1 = cadd(s1, s3);
        float2 m0 = csub(s0, s2), m1 = csub(s1, s3);
        m1 = make_float2(m1.y, -m1.x);
        a[0] = cadd(p0, p1); a[4] = csub(p0, p1);
        a[2] = cadd(m0, m1); a[6] = csub(m0, m1);
    }
    {
        float2 p0 = cadd(d0, d2), p1 = cadd(d1, d3);
        float2 m0 = csub(d0, d2), m1 = csub(d1, d3);
        m1 = make_float2(m1.y, -m1.x);
        a[1] = cadd(p0, p1); a[5] = csub(p0, p1);
        a[3] = cadd(m0, m1); a[7] = csub(m0, m1);
    }
}

__device__ inline void dft4(float2 a[4]) {
    float2 p0 = cadd(a[0], a[2]), p1 = cadd(a[1], a[3]);
    float2 m0 = csub(a[0], a[2]), m1 = csub(a[1], a[3]);
    m1 = make_float2(m1.y, -m1.x);
    a[0] = cadd(p0, p1); a[2] = csub(p0, p1);
    a[1] = cadd(m0, m1); a[3] = csub(m0, m1);
}

// Radix-8 Stockham DIF stage — proven r3-r9, verbatim.
template <int N, int S, int NT>
__device__ inline void stage8(float2* __restrict__ lds, int tid) {
    constexpr int NB = N / 8;
    constexpr int ITER = (NB + NT - 1) / NT;
    const bool act = (NB >= NT) || (tid < NB);
    float2 d[ITER][8];
#pragma unroll
    for (int b = 0; b < ITER; ++b) {
        const int u = tid + b * NT;
        if (act) {
#pragma unroll
            for (int j = 0; j < 8; ++j)
                d[b][j] = lds[SZ(u + NB * j)];
        }
    }
    __syncthreads();
#pragma unroll
    for (int b = 0; b < ITER; ++b) {
        const int u = tid + b * NT;
        if (act) {
            const int q = u & (S - 1);
            dft8(d[b]);
            if constexpr (S < NB) {
                const float cang = (float)(-6.283185307179586) / (float)N;
                float sn, cs;
                __sincosf(cang * (float)(u - q), &sn, &cs);
                const float2 w = make_float2(cs, sn);
                float2 t = w;
#pragma unroll
                for (int k = 1; k < 8; ++k) {
                    d[b][k] = cmul(d[b][k], t);
                    if (k < 7) t = cmul(t, w);
                }
            }
            const int base = 8 * u - 7 * q;
#pragma unroll
            for (int k = 0; k < 8; ++k)
                lds[SZ(base + k * S)] = d[b][k];
        }
    }
    __syncthreads();
}

// Radix-4 Stockham stage — proven r5.
template <int N, int S, int NT>
__device__ inline void stage4(float2* __restrict__ lds, int tid) {
    constexpr int NB = N / 4;
    constexpr int ITER = (NB + NT - 1) / NT;
    const bool act = (NB >= NT) || (tid < NB);
    float2 d[ITER][4];
#pragma unroll
    for (int b = 0; b < ITER; ++b) {
        const int u = tid + b * NT;
        if (act) {
#pragma unroll
            for (int j = 0; j < 4; ++j)
                d[b][j] = lds[SZ(u + NB * j)];
        }
    }
    __syncthreads();
#pragma unroll
    for (int b = 0; b < ITER; ++b) {
        const int u = tid + b * NT;
        if (act) {
            const int q = u & (S - 1);
            dft4(d[b]);
            if constexpr (S < NB) {
                const float cang = (float)(-6.283185307179586) / (float)N;
                float sn, cs;
                __sincosf(cang * (float)(u - q), &sn, &cs);
                const float2 w = make_float2(cs, sn);
                float2 t = w;
#pragma unroll
                for (int k = 1; k < 4; ++k) {
                    d[b][k] = cmul(d[b][k], t);
                    if (k < 3) t = cmul(t, w);
                }
            }
            const int base = 4 * u - 3 * q;
#pragma unroll
            for (int k = 0; k < 4; ++k)
                lds[SZ(base + k * S)] = d[b][k];
        }
    }
    __syncthreads();
}

// First stage of cfft4096 with zero top half — proven r8/r9.
__device__ inline void halfzero4096_writeback(float2* __restrict__ lds, int tid,
                                              float2 a0, float2 a1,
                                              float2 a2, float2 a3) {
    const float C = 0.70710678118654752f;
    __syncthreads();
    float2 p0 = cadd(a0, a2), p1 = cadd(a1, a3);
    float2 m0 = csub(a0, a2), m1t = csub(a1, a3);
    float2 m1 = make_float2(m1t.y, -m1t.x);
    float2 b0 = cadd(p0, p1), b4 = csub(p0, p1);
    float2 b2 = cadd(m0, m1), b6 = csub(m0, m1);
    float2 c1 = make_float2(C * (a1.x + a1.y), C * (a1.y - a1.x));
    float2 c2 = make_float2(a2.y, -a2.x);
    float2 c3 = make_float2(C * (a3.y - a3.x), -C * (a3.x + a3.y));
    float2 q0 = cadd(a0, c2), q1 = cadd(c1, c3);
    float2 n0 = csub(a0, c2), n1t = csub(c1, c3);
    float2 n1 = make_float2(n1t.y, -n1t.x);
    float2 b1 = cadd(q0, q1), b5 = csub(q0, q1);
    float2 b3 = cadd(n0, n1), b7 = csub(n0, n1);
    float sn, cs;
    __sincosf((float)(-6.283185307179586 / 4096.0) * (float)tid, &sn, &cs);
    float2 w1 = make_float2(cs, sn);
    float2 w2 = cmul(w1, w1), w3 = cmul(w2, w1), w4 = cmul(w2, w2);
    float2 w5 = cmul(w3, w2), w6 = cmul(w3, w3), w7 = cmul(w4, w3);
    const int base = 8 * tid;
    lds[SZ(base + 0)] = b0;
    lds[SZ(base + 1)] = cmul(b1, w1);
    lds[SZ(base + 2)] = cmul(b2, w2);
    lds[SZ(base + 3)] = cmul(b3, w3);
    lds[SZ(base + 4)] = cmul(b4, w4);
    lds[SZ(base + 5)] = cmul(b5, w5);
    lds[SZ(base + 6)] = cmul(b6, w6);
    lds[SZ(base + 7)] = cmul(b7, w7);
    __syncthreads();
}

// K_hat single bin — body proven r2-r9.
__device__ inline float2 khat_bin(int i, int k,
                                  const float* __restrict__ Bm,
                                  const float* __restrict__ Cm,
                                  const float* __restrict__ Lm,
                                  const float* __restrict__ Pm,
                                  const float* __restrict__ Qm) {
    float theta = (float)(6.283185307179586 / (double)SEQ) * (float)k;
    float sn, cs;
    sincosf(theta, &sn, &cs);
    float tr = 1.0f - cs, ti = -sn;
    float br = 1.0f + cs, bi = sn;
    float idn = 1.0f / (br * br + bi * bi);
    float gr = 20.0f * (tr * br + ti * bi) * idn;
    float gi = 20.0f * (ti * br - tr * bi) * idn;
    float cr = 2.0f * br * idn;
    float ci = -2.0f * bi * idn;

    const float* Brow = Bm + i * H_DIM;
    const float* Crow = Cm + i * H_DIM;
    const float* Lrow = Lm + i * H_DIM;
    const float* Prow = Pm + i * H_DIM;
    const float* Qrow = Qm + i * H_DIM;

    float k00r = 0.f, k00i = 0.f, k01r = 0.f, k01i = 0.f;
    float k10r = 0.f, k10i = 0.f, k11r = 0.f, k11i = 0.f;
#pragma unroll 8
    for (int h = 0; h < H_DIM; ++h) {
        float lam = Lrow[h];
        float drr = gr - lam;
        float dii = gi;
        float im = 1.0f / (drr * drr + dii * dii);
        float ivr = drr * im;
        float ivi = -dii * im;
        float bv = Brow[h], cv = Crow[h], pv = Prow[h], qv = Qrow[h];
        float cb = cv * bv;
        float cp = cv * pv;
        float qb = qv * bv;
        float qp = qv * pv;
        k00r += cb * ivr; k00i += cb * ivi;
        k01r += cp * ivr; k01i += cp * ivi;
        k10r += qb * ivr; k10i += qb * ivi;
        k11r += qp * ivr; k11i += qp * ivi;
    }
    float t1r = 1.0f + k11r, t1i = k11i;
    float t2r = k01r * t1r - k01i * t1i;
    float t2i = k01r * t1i + k01i * t1r;
    float t3r = t2r * k10r - t2i * k10i;
    float t3i = t2r * k10i + t2i * k10r;
    float nr = k00r - t3r, ni = k00i - t3i;
    return make_float2(cr * nr - ci * ni, cr * ni + ci * nr);
}

// ===========================================================================
// Kernel 1: tiled transpose x[b][n][i] -> xT[b][i][n]  (+ khat spread over
// all 1024 blocks: 2048 bins x 128 ch = 256 bins/block, 1/thread).
// ===========================================================================
__global__ __launch_bounds__(256) void k1_transpose_khat(const float* __restrict__ x,
                                                         const float* __restrict__ Bm,
                                                         const float* __restrict__ Cm,
                                                         const float* __restrict__ Lm,
                                                         const float* __restrict__ Pm,
                                                         const float* __restrict__ Qm) {
    __shared__ float t[64][65];
    const int blk = blockIdx.x;          // 0..1023
    const int b = blk >> 7;              // 0..7
    const int rest = blk & 127;
    const int nt = rest >> 1;            // 0..63
    const int it = rest & 1;             // 0..1
    const int tx = threadIdx.x & 63;
    const int ty = threadIdx.x >> 6;     // 0..3
    const int n0 = nt * 64, i0 = it * 64;

    const float* xb = x + (size_t)b * SEQ * I_DIM;
#pragma unroll
    for (int r = 0; r < 16; ++r) {
        int nl = r * 4 + ty;
        t[nl][tx] = xb[(size_t)(n0 + nl) * I_DIM + i0 + tx];   // coalesced in i
    }
    __syncthreads();
#pragma unroll
    for (int r = 0; r < 16; ++r) {
        int il = r * 4 + ty;
        g_xT[((size_t)b * I_DIM + i0 + il) * SEQ + n0 + tx] = t[tx][il];  // coalesced in n
    }

    // khat: ch = blk>>3 (0..127), slice = blk&7, k = slice*256 + tid (0..2047)
    const int ch = blk >> 3, sl = blk & 7;
    const int k = sl * 256 + threadIdx.x;
    g_Hh[(size_t)ch * NBIN + k] = khat_bin(ch, k, Bm, Cm, Lm, Pm, Qm);
    if (sl == 0 && threadIdx.x == 0)
        g_Hh[(size_t)ch * NBIN + 2048] = khat_bin(ch, 2048, Bm, Cm, Lm, Pm, Qm);
}

// ===========================================================================
// Kernel 2: blocks [0,128) -> kprep (r5-proven, g_Hh -> g_Kf)
//           blocks [128,1152) -> fwd cfft4096 from xT (coalesced float2)
// ===========================================================================
__global__ __launch_bounds__(512) void k2_kprep_fwd() {
    __shared__ float2 lds[4096];
    const int tid = threadIdx.x;

    if (blockIdx.x < I_DIM) {
        const int i = blockIdx.x;
        const float2* Hrow = g_Hh + (size_t)i * NBIN;
#pragma unroll
        for (int r = 0; r < 4; ++r) {
            int m = tid + (r << 9);
            float2 Hm = Hrow[m];
            float2 Hc = Hrow[2048 - m];
            float pr = Hm.x + Hc.x, pi2 = Hm.y - Hc.y;
            float dr = Hm.x - Hc.x, di = Hm.y + Hc.y;
            float sn, cs;
            __sincosf((float)(3.141592653589793 / 2048.0) * (float)m, &sn, &cs);
            float Or = 0.5f * (cs * dr - sn * di);
            float Oi = 0.5f * (sn * dr + cs * di);
            lds[SZ(m)] = make_float2(0.5f * pr - Oi, -(0.5f * pi2 + Or));
        }
        __syncthreads();

        stage4<2048, 1,   512>(lds, tid);
        stage8<2048, 4,   512>(lds, tid);
        stage8<2048, 32,  512>(lds, tid);
        stage8<2048, 256, 512>(lds, tid);

        const float s1 = 1.0f / 2048.0f;
        float2 a[4];
#pragma unroll
        for (int j = 0; j < 4; ++j) {
            float2 o = lds[SZ(tid + (j << 9))];
            a[j] = make_float2(o.x * s1, -o.y * s1);
        }
        halfzero4096_writeback(lds, tid, a[0], a[1], a[2], a[3]);

        stage8<4096, 8,   512>(lds, tid);
        stage8<4096, 64,  512>(lds, tid);
        stage8<4096, 512, 512>(lds, tid);

        float2* Kfrow = g_Kf + (size_t)i * NBIN2;
#pragma unroll
        for (int r = 0; r < 9; ++r) {
            int m = tid + (r << 9);
            if (m <= 4096) {
                float2 Zq = lds[SZ(m & 4095)];
                float2 Zr = lds[SZ((4096 - m) & 4095)];
                float sn, cs;
                __sincosf((float)(-3.141592653589793 / 4096.0) * (float)m, &sn, &cs);
                float pr = Zq.x + Zr.x, pi2 = Zq.y - Zr.y;
                float dr = Zq.x - Zr.x, di = Zq.y + Zr.y;
                float jt_r = -sn * dr - cs * di;
                float jt_i =  cs * dr - sn * di;
                Kfrow[m] = make_float2(0.5f * (pr - jt_r), 0.5f * (pi2 - jt_i));
            }
        }
    } else {
        const int blk = blockIdx.x - I_DIM;      // 0..1023
        const int b = blk & 7;
        const int i = blk >> 3;

        // coalesced pack: z[n] = xT[2n] + j*xT[2n+1] = float2 load
        const float2* xrow = (const float2*)(g_xT + ((size_t)b * I_DIM + i) * SEQ);
        float2 a0 = xrow[tid];
        float2 a1 = xrow[tid + 512];
        float2 a2 = xrow[tid + 1024];
        float2 a3 = xrow[tid + 1536];
        halfzero4096_writeback(lds, tid, a0, a1, a2, a3);

        stage8<4096, 8,  512>(lds, tid);
        stage8<4096, 64, 512>(lds, tid);

        // last stage (S=512, twiddle-free) fused with coalesced g_Xf store
        float2 e[8];
#pragma unroll
        for (int j = 0; j < 8; ++j) e[j] = lds[SZ(tid + (j << 9))];
        dft8(e);
        float2* dst = g_Xf + (size_t)blk * SEQ;
#pragma unroll
        for (int k = 0; k < 8; ++k)
            dst[tid + (k << 9)] = e[k];
    }
}

// ===========================================================================
// Kernel 3: fused combine + inverse cfft4096 -> yT (coalesced float2 stores).
// ===========================================================================
__global__ __launch_bounds__(512) void k3_combine_inv() {
    __shared__ float2 lds[4096];
    const int tid = threadIdx.x;
    const int blk = blockIdx.x;
    const int b = blk & 7;
    const int i = blk >> 3;
    const float2* Xf = g_Xf + (size_t)blk * SEQ;
    const float2* Kfrow = g_Kf + (size_t)i * NBIN2;

    float2 d[8];
#pragma unroll
    for (int j = 0; j < 8; ++j) {
        int m = tid + (j << 9);
        int mm = (4096 - m) & 4095;
        float2 Zq = Xf[m];
        float2 Zr = Xf[mm];
        float2 Km  = Kfrow[m];
        float2 Km2 = Kfrow[4096 - m];
        float sn, cs;
        __sincosf((float)(-3.141592653589793 / 4096.0) * (float)m, &sn, &cs);
        float pr = Zq.x + Zr.x, pi2 = Zq.y - Zr.y;
        float dr = Zq.x - Zr.x, di = Zq.y + Zr.y;
        float jt_r = -sn * dr - cs * di;
        float jt_i =  cs * dr - sn * di;
        float2 Xm  = make_float2(0.5f * (pr - jt_r),  0.5f * ( pi2 - jt_i));
        float2 Xm2 = make_float2(0.5f * (pr + jt_r),  0.5f * (-pi2 - jt_i));
        float2 Ym  = cmul(Xm,  Km);
        float2 Ym2 = cmul(Xm2, Km2);
        float qr = Ym.x + Ym2.x, qi = Ym.y - Ym2.y;
        float er = Ym.x - Ym2.x, ei = Ym.y + Ym2.y;
        float gr2 = sn * er - cs * ei;
        float gi2 = sn * ei + cs * er;
        d[j] = make_float2(0.5f * (qr + gr2), -0.5f * (qi + gi2));  // conjZy[m]
    }

    dft8(d);
    {
        float sn, cs;
        __sincosf((float)(-6.283185307179586 / 4096.0) * (float)tid, &sn, &cs);
        float2 w1 = make_float2(cs, sn);
        float2 w2 = cmul(w1, w1), w3 = cmul(w2, w1), w4 = cmul(w2, w2);
        float2 w5 = cmul(w3, w2), w6 = cmul(w3, w3), w7 = cmul(w4, w3);
        d[1] = cmul(d[1], w1); d[2] = cmul(d[2], w2); d[3] = cmul(d[3], w3);
        d[4] = cmul(d[4], w4); d[5] = cmul(d[5], w5); d[6] = cmul(d[6], w6);
        d[7] = cmul(d[7], w7);
    }
    const int base = 8 * tid;
#pragma unroll
    for (int k = 0; k < 8; ++k) lds[SZ(base + k)] = d[k];
    __syncthreads();

    stage8<4096, 8,  512>(lds, tid);
    stage8<4096, 64, 512>(lds, tid);

    // last stage (S=512, twiddle-free) fused with coalesced yT store
    float2 e[8];
#pragma unroll
    for (int j = 0; j < 8; ++j) e[j] = lds[SZ(tid + (j << 9))];
    dft8(e);
    const float inv = 1.0f / 4096.0f;
    float2* yrow = (float2*)(g_Yt + ((size_t)b * I_DIM + i) * SEQ);
#pragma unroll
    for (int k = 0; k < 4; ++k)
        yrow[tid + (k << 9)] = make_float2(e[k].x * inv, -e[k].y * inv);
}

// ===========================================================================
// Kernel 4: tiled transpose yT[b][i][n] -> y[b][n][i].
// ===========================================================================
__global__ __launch_bounds__(256) void k4_transpose_out(float* __restrict__ y) {
    __shared__ float t[64][65];
    const int blk = blockIdx.x;          // 0..1023
    const int b = blk >> 7;
    const int rest = blk & 127;
    const int nt = rest >> 1;            // 0..63
    const int it = rest & 1;             // 0..1
    const int tx = threadIdx.x & 63;
    const int ty = threadIdx.x >> 6;
    const int n0 = nt * 64, i0 = it * 64;

#pragma unroll
    for (int r = 0; r < 16; ++r) {
        int il = r * 4 + ty;
        t[il][tx] = g_Yt[((size_t)b * I_DIM + i0 + il) * SEQ + n0 + tx];  // coalesced in n
    }
    __syncthreads();
    float* yb = y + (size_t)b * SEQ * I_DIM;
#pragma unroll
    for (int r = 0; r < 16; ++r) {
        int nl = r * 4 + ty;
        yb[(size_t)(n0 + nl) * I_DIM + i0 + tx] = t[tx][nl];              // coalesced in i
    }
}

// ---------------------------------------------------------------------------
extern "C" void kernel_launch(void* const* d_in, const int* in_sizes, int n_in,
                              void* d_out, int out_size, void* d_ws, size_t ws_size,
                              hipStream_t stream) {
    const float* x  = (const float*)d_in[0];
    const float* Bm = (const float*)d_in[1];
    const float* Cm = (const float*)d_in[2];
    const float* Lm = (const float*)d_in[3];
    const float* Pm = (const float*)d_in[4];
    const float* Qm = (const float*)d_in[5];
    float* out = (float*)d_out;

    k1_transpose_khat<<<1024, 256, 0, stream>>>(x, Bm, Cm, Lm, Pm, Qm);
    k2_kprep_fwd<<<I_DIM + BATCH * I_DIM, 512, 0, stream>>>();
    k3_combine_inv<<<BATCH * I_DIM, 512, 0, stream>>>();
    k4_transpose_out<<<1024, 256, 0, stream>>>(out);
}